// Round 1
// baseline (741.752 us; speedup 1.0000x reference)
//
#include <hip/hip_runtime.h>
#include <hip/hip_bf16.h>
#include <cstdint>
#include <cstddef>

// Problem constants
#define T_TOK 4096
#define DD    1024
#define II    512
#define NE    32     // routed experts
#define NE1   33     // + shared expert as expert 32
#define CAP   4096   // per-expert token-list capacity
#define NGROUP 8
#define TOPKG  4
#define TOPK   8

typedef __bf16 bf16;
typedef __bf16 bf16x8 __attribute__((ext_vector_type(8)));
typedef float  f32x4  __attribute__((ext_vector_type(4)));

// GEMM tile
#define BM 128
#define BN 64
#define BK 32

// Workspace layout (bytes)
#define OFF_X      0u               // T*D bf16 = 8,388,608
#define OFF_COUNTS 8388608u         // 33 ints (reserve 512)
#define OFF_TOKS   8389120u         // 33*4096 ints = 540,672
#define OFF_WTS    8929792u         // 33*4096 floats = 540,672
#define OFF_H      9470464u         // 36864*512 bf16 = 37,748,736
#define WS_NEEDED  47219200u

// ---------------------------------------------------------------- init
__global__ void init_kernel(int* __restrict__ counts, int* __restrict__ toks,
                            float* __restrict__ wts) {
    int i = blockIdx.x * 256 + threadIdx.x;
    if (i < NE1) counts[i] = (i == NE) ? T_TOK : 0;
    if (i < T_TOK) {                       // shared expert token list
        toks[NE * CAP + i] = i;
        wts[NE * CAP + i] = 1.0f;
    }
}

// ---------------------------------------------------------------- X -> bf16
__global__ void convert_x_kernel(const float* __restrict__ X, bf16* __restrict__ Xb) {
    int i = blockIdx.x * 256 + threadIdx.x;   // i < T*D/4
    float4 v = ((const float4*)X)[i];
    union { bf16 b[4]; uint2 u; } p;
    p.b[0] = (bf16)v.x; p.b[1] = (bf16)v.y; p.b[2] = (bf16)v.z; p.b[3] = (bf16)v.w;
    ((uint2*)Xb)[i] = p.u;
}

// ---------------------------------------------------------------- routing
__global__ __launch_bounds__(256) void routing_kernel(
    const float* __restrict__ X, const float* __restrict__ gate_w,
    float* __restrict__ logits, int* __restrict__ counts,
    int* __restrict__ toks, float* __restrict__ wts)
{
    const int t = blockIdx.x;
    const int tid = threadIdx.x;
    __shared__ float xs[DD];
    ((float4*)xs)[tid] = ((const float4*)(X + (size_t)t * DD))[tid];
    __syncthreads();

    // 8 lanes per expert, contiguous chunks of 128
    const int e = tid >> 3, q = tid & 7;
    const float* wrow = gate_w + e * DD + q * 128;
    const float* xv = xs + q * 128;
    float p = 0.f;
    #pragma unroll 8
    for (int j = 0; j < 128; ++j) p += xv[j] * wrow[j];
    p += __shfl_down(p, 4);
    p += __shfl_down(p, 2);
    p += __shfl_down(p, 1);
    __shared__ float lg[NE];
    if (q == 0) { lg[e] = p; logits[(size_t)t * NE + e] = p; }
    __syncthreads();

    if (tid == 0) {
        float sc[NE];
        for (int i = 0; i < NE; ++i) sc[i] = 1.f / (1.f + expf(-lg[i]));
        float gs[NGROUP];
        for (int g = 0; g < NGROUP; ++g)
            gs[g] = sc[g * 4 + 0] + sc[g * 4 + 1] + sc[g * 4 + 2] + sc[g * 4 + 3];
        unsigned gmask = 0;
        for (int it = 0; it < TOPKG; ++it) {   // strict > == first-index tie policy
            int best = 0; float bv = -1e30f;
            for (int g = 0; g < NGROUP; ++g)
                if (!((gmask >> g) & 1) && gs[g] > bv) { bv = gs[g]; best = g; }
            gmask |= 1u << best;
        }
        float ms[NE];
        for (int i = 0; i < NE; ++i)
            ms[i] = ((gmask >> (i >> 2)) & 1) ? sc[i] : 0.f;
        int idx[TOPK]; float wv[TOPK]; float sum = 0.f;
        unsigned used = 0;
        for (int it = 0; it < TOPK; ++it) {
            int best = 0; float bv = -1e30f;
            for (int i = 0; i < NE; ++i)
                if (!((used >> i) & 1) && ms[i] > bv) { bv = ms[i]; best = i; }
            used |= 1u << best;
            idx[it] = best; wv[it] = bv; sum += bv;
        }
        float inv = 1.f / fmaxf(sum, 1e-12f);
        for (int it = 0; it < TOPK; ++it) {
            int ee = idx[it];
            int slot = atomicAdd(&counts[ee], 1);
            toks[ee * CAP + slot] = t;
            wts[ee * CAP + slot] = wv[it] * inv;
        }
    }
}

// ---------------------------------------------------------------- gate+up GEMM
// C[m][n] = sum_k A[m][k]*B[n][k]; MFMA 16x16x32 bf16.
// A frag: lane holds A[m=lane&15][k=(lane>>4)*8+j]; B frag symmetric (row=n).
// C/D: row=(lane>>4)*4+reg, col=lane&15  [m89-verified mapping]
__global__ __launch_bounds__(256) void gateup_kernel(
    const bf16* __restrict__ Xb,
    const float* __restrict__ eg, const float* __restrict__ eu,
    const float* __restrict__ sg, const float* __restrict__ su,
    const int* __restrict__ counts, const int* __restrict__ toks,
    const float* __restrict__ wts, bf16* __restrict__ H)
{
    const int e = blockIdx.z;
    const int n_e = counts[e];
    const int m0 = blockIdx.y * BM;
    if (m0 >= n_e) return;
    int offs = 0;
    for (int i = 0; i < e; ++i) offs += counts[i];
    const int n0 = blockIdx.x * BN;
    const float* wg = (e < NE) ? eg + (size_t)e * II * DD : sg;
    const float* wu = (e < NE) ? eu + (size_t)e * II * DD : su;

    __shared__ __align__(16) bf16 As[BM * BK];
    __shared__ __align__(16) bf16 Bg[BN * BK];
    __shared__ __align__(16) bf16 Bu[BN * BK];
    __shared__ int   tokS[BM];
    __shared__ float wtS[BM];

    const int tid = threadIdx.x;
    if (tid < BM) {
        int r = m0 + tid;
        int tk = 0; float w = 0.f;
        if (r < n_e) { tk = toks[e * CAP + r]; w = wts[e * CAP + r]; }
        tokS[tid] = tk; wtS[tid] = w;
    }
    __syncthreads();

    const int lane = tid & 63;
    const int wv = tid >> 6;
    const int wm = (wv & 1) * 64;
    const int wn = (wv >> 1) * 32;
    const int lr = lane & 15;
    const int lq = lane >> 4;

    f32x4 accG[4][2], accU[4][2];
    #pragma unroll
    for (int i = 0; i < 4; ++i)
        #pragma unroll
        for (int j = 0; j < 2; ++j) {
            accG[i][j] = f32x4{0.f, 0.f, 0.f, 0.f};
            accU[i][j] = f32x4{0.f, 0.f, 0.f, 0.f};
        }

    const int srow = tid >> 2;          // 0..63
    const int skq  = (tid & 3) * 8;     // k offset in elems

    for (int kt = 0; kt < DD; kt += BK) {
        // stage A (gathered bf16 rows), 2 rows/thread
        #pragma unroll
        for (int h = 0; h < 2; ++h) {
            int r = srow + h * 64;
            int tk = tokS[r];
            uint4 v = *(const uint4*)(Xb + (size_t)tk * DD + kt + skq);
            *(uint4*)(As + r * BK + skq) = v;
        }
        // stage B gate & up (fp32 -> bf16 on the fly)
        {
            const float* pg = wg + (size_t)(n0 + srow) * DD + kt + skq;
            float4 g0 = ((const float4*)pg)[0];
            float4 g1 = ((const float4*)pg)[1];
            bf16x8 vg;
            vg[0] = (bf16)g0.x; vg[1] = (bf16)g0.y; vg[2] = (bf16)g0.z; vg[3] = (bf16)g0.w;
            vg[4] = (bf16)g1.x; vg[5] = (bf16)g1.y; vg[6] = (bf16)g1.z; vg[7] = (bf16)g1.w;
            *(bf16x8*)(Bg + srow * BK + skq) = vg;
            const float* pu = wu + (size_t)(n0 + srow) * DD + kt + skq;
            float4 u0 = ((const float4*)pu)[0];
            float4 u1 = ((const float4*)pu)[1];
            bf16x8 vu;
            vu[0] = (bf16)u0.x; vu[1] = (bf16)u0.y; vu[2] = (bf16)u0.z; vu[3] = (bf16)u0.w;
            vu[4] = (bf16)u1.x; vu[5] = (bf16)u1.y; vu[6] = (bf16)u1.z; vu[7] = (bf16)u1.w;
            *(bf16x8*)(Bu + srow * BK + skq) = vu;
        }
        __syncthreads();

        bf16x8 af[4];
        #pragma unroll
        for (int mt = 0; mt < 4; ++mt)
            af[mt] = *(const bf16x8*)(As + (wm + mt * 16 + lr) * BK + lq * 8);
        #pragma unroll
        for (int nt = 0; nt < 2; ++nt) {
            bf16x8 bg = *(const bf16x8*)(Bg + (wn + nt * 16 + lr) * BK + lq * 8);
            bf16x8 bu = *(const bf16x8*)(Bu + (wn + nt * 16 + lr) * BK + lq * 8);
            #pragma unroll
            for (int mt = 0; mt < 4; ++mt) {
                accG[mt][nt] = __builtin_amdgcn_mfma_f32_16x16x32_bf16(af[mt], bg, accG[mt][nt], 0, 0, 0);
                accU[mt][nt] = __builtin_amdgcn_mfma_f32_16x16x32_bf16(af[mt], bu, accU[mt][nt], 0, 0, 0);
            }
        }
        __syncthreads();
    }

    // epilogue: h = silu(g)*u*route_w  -> H (bf16)
    #pragma unroll
    for (int mt = 0; mt < 4; ++mt) {
        #pragma unroll
        for (int r = 0; r < 4; ++r) {
            int mrow = wm + mt * 16 + lq * 4 + r;
            if (m0 + mrow < n_e) {
                float w = wtS[mrow];
                #pragma unroll
                for (int nt = 0; nt < 2; ++nt) {
                    float g = accG[mt][nt][r];
                    float u = accU[mt][nt][r];
                    float hval = g / (1.f + __expf(-g)) * u * w;
                    H[(size_t)(offs + m0 + mrow) * II + (n0 + wn + nt * 16 + lr)] = (bf16)hval;
                }
            }
        }
    }
}

// ---------------------------------------------------------------- down GEMM + combine
__global__ __launch_bounds__(256) void down_kernel(
    const bf16* __restrict__ H,
    const float* __restrict__ ed, const float* __restrict__ sd,
    const int* __restrict__ counts, const int* __restrict__ toks,
    float* __restrict__ out)
{
    const int e = blockIdx.z;
    const int n_e = counts[e];
    const int m0 = blockIdx.y * BM;
    if (m0 >= n_e) return;
    int offs = 0;
    for (int i = 0; i < e; ++i) offs += counts[i];
    const int n0 = blockIdx.x * BN;
    const float* wd = (e < NE) ? ed + (size_t)e * DD * II : sd;

    __shared__ __align__(16) bf16 As[BM * BK];
    __shared__ __align__(16) bf16 Bs[BN * BK];
    __shared__ int tokS[BM];

    const int tid = threadIdx.x;
    if (tid < BM) {
        int r = m0 + tid;
        tokS[tid] = (r < n_e) ? toks[e * CAP + r] : 0;
    }
    __syncthreads();

    const int lane = tid & 63;
    const int wv = tid >> 6;
    const int wm = (wv & 1) * 64;
    const int wn = (wv >> 1) * 32;
    const int lr = lane & 15;
    const int lq = lane >> 4;

    f32x4 acc[4][2];
    #pragma unroll
    for (int i = 0; i < 4; ++i)
        #pragma unroll
        for (int j = 0; j < 2; ++j) acc[i][j] = f32x4{0.f, 0.f, 0.f, 0.f};

    const int srow = tid >> 2;
    const int skq  = (tid & 3) * 8;

    for (int kt = 0; kt < II; kt += BK) {
        #pragma unroll
        for (int h = 0; h < 2; ++h) {
            int r = srow + h * 64;
            int hr = m0 + r; if (hr >= n_e) hr = n_e - 1;  // clamp: padded rows unstored
            uint4 v = *(const uint4*)(H + (size_t)(offs + hr) * II + kt + skq);
            *(uint4*)(As + r * BK + skq) = v;
        }
        {
            const float* pd = wd + (size_t)(n0 + srow) * II + kt + skq;
            float4 d0 = ((const float4*)pd)[0];
            float4 d1 = ((const float4*)pd)[1];
            bf16x8 vd;
            vd[0] = (bf16)d0.x; vd[1] = (bf16)d0.y; vd[2] = (bf16)d0.z; vd[3] = (bf16)d0.w;
            vd[4] = (bf16)d1.x; vd[5] = (bf16)d1.y; vd[6] = (bf16)d1.z; vd[7] = (bf16)d1.w;
            *(bf16x8*)(Bs + srow * BK + skq) = vd;
        }
        __syncthreads();

        bf16x8 af[4];
        #pragma unroll
        for (int mt = 0; mt < 4; ++mt)
            af[mt] = *(const bf16x8*)(As + (wm + mt * 16 + lr) * BK + lq * 8);
        #pragma unroll
        for (int nt = 0; nt < 2; ++nt) {
            bf16x8 bd = *(const bf16x8*)(Bs + (wn + nt * 16 + lr) * BK + lq * 8);
            #pragma unroll
            for (int mt = 0; mt < 4; ++mt)
                acc[mt][nt] = __builtin_amdgcn_mfma_f32_16x16x32_bf16(af[mt], bd, acc[mt][nt], 0, 0, 0);
        }
        __syncthreads();
    }

    #pragma unroll
    for (int mt = 0; mt < 4; ++mt) {
        #pragma unroll
        for (int r = 0; r < 4; ++r) {
            int mrow = wm + mt * 16 + lq * 4 + r;
            if (m0 + mrow < n_e) {
                int tok = tokS[mrow];
                #pragma unroll
                for (int nt = 0; nt < 2; ++nt)
                    atomicAdd(out + (size_t)tok * DD + (n0 + wn + nt * 16 + lr),
                              acc[mt][nt][r]);
            }
        }
    }
}

// ---------------------------------------------------------------- launch
extern "C" void kernel_launch(void* const* d_in, const int* in_sizes, int n_in,
                              void* d_out, int out_size, void* d_ws, size_t ws_size,
                              hipStream_t stream) {
    if (ws_size < WS_NEEDED) return;  // avoid corrupting memory if ws too small

    const float* X  = (const float*)d_in[0];
    const float* gw = (const float*)d_in[1];
    const float* eg = (const float*)d_in[2];
    const float* eu = (const float*)d_in[3];
    const float* ed = (const float*)d_in[4];
    const float* sg = (const float*)d_in[5];
    const float* su = (const float*)d_in[6];
    const float* sd = (const float*)d_in[7];
    float* out = (float*)d_out;
    char* ws = (char*)d_ws;

    bf16*  Xb     = (bf16*)(ws + OFF_X);
    int*   counts = (int*)(ws + OFF_COUNTS);
    int*   toks   = (int*)(ws + OFF_TOKS);
    float* wts    = (float*)(ws + OFF_WTS);
    bf16*  H      = (bf16*)(ws + OFF_H);
    float* logits = out + (size_t)T_TOK * DD;

    hipMemsetAsync(out, 0, (size_t)T_TOK * DD * sizeof(float), stream);
    init_kernel<<<16, 256, 0, stream>>>(counts, toks, wts);
    convert_x_kernel<<<(T_TOK * DD / 4) / 256, 256, 0, stream>>>(X, Xb);
    routing_kernel<<<T_TOK, 256, 0, stream>>>(X, gw, logits, counts, toks, wts);
    gateup_kernel<<<dim3(II / BN, T_TOK / BM, NE1), 256, 0, stream>>>(
        Xb, eg, eu, sg, su, counts, toks, wts, H);
    down_kernel<<<dim3(DD / BN, T_TOK / BM, NE1), 256, 0, stream>>>(
        H, ed, sd, counts, toks, out);
}

// Round 2
// 689.273 us; speedup vs baseline: 1.0761x; 1.0761x over previous
//
#include <hip/hip_runtime.h>
#include <hip/hip_bf16.h>
#include <cstdint>
#include <cstddef>

// Problem constants
#define T_TOK 4096
#define DD    1024
#define II    512
#define NE    32     // routed experts
#define NE1   33     // + shared expert as expert 32
#define CAP   4096   // per-expert token-list capacity
#define NGROUP 8
#define TOPKG  4
#define TOPK   8

typedef __bf16 bf16;
typedef __bf16 bf16x8 __attribute__((ext_vector_type(8)));
typedef float  f32x4  __attribute__((ext_vector_type(4)));

// GEMM tile (fallback fp32-staging path)
#define BM 128
#define BN 64
#define BK 32
// bf16-weight path K tile
#define BK2 64

// Workspace layout (bytes)
#define OFF_X      0u               // T*D bf16 = 8,388,608
#define OFF_COUNTS 8388608u         // counts 33 ints @+0, offsets 34 ints @+256
#define OFF_TOKS   8389120u         // 33*4096 ints = 540,672
#define OFF_WTS    8929792u         // 33*4096 floats = 540,672
#define OFF_H      9470464u         // 36864*512 bf16 = 37,748,736
#define WS_MIN     47219200u
// bf16 weights (full path)
#define OFF_EGB    47219200u        // 32*512*1024*2 = 33,554,432
#define OFF_EUB    80773632u
#define OFF_EDB    114328064u
#define OFF_SGB    147882496u       // 512*1024*2 = 1,048,576
#define OFF_SUB    148931072u
#define OFF_SDB    149979648u
#define WS_FULL    151028224u

// async global->LDS, 16B per lane; LDS dest must be wave-uniform base
#define GLDS(g, l) __builtin_amdgcn_global_load_lds( \
    (const __attribute__((address_space(1))) void*)(g), \
    (__attribute__((address_space(3))) void*)(l), 16, 0, 0)

// ---------------------------------------------------------------- init
__global__ void init_kernel(int* __restrict__ counts, int* __restrict__ toks,
                            float* __restrict__ wts) {
    int i = blockIdx.x * 256 + threadIdx.x;
    if (i < NE1) counts[i] = (i == NE) ? T_TOK : 0;
    if (i < T_TOK) {                       // shared expert token list
        toks[NE * CAP + i] = i;
        wts[NE * CAP + i] = 1.0f;
    }
}

// ---------------------------------------------------------------- fp32 -> bf16
__global__ void convert_kernel(const float* __restrict__ src, bf16* __restrict__ dst) {
    int i = blockIdx.x * 256 + threadIdx.x;   // i < n/4
    float4 v = ((const float4*)src)[i];
    union { bf16 b[4]; uint2 u; } p;
    p.b[0] = (bf16)v.x; p.b[1] = (bf16)v.y; p.b[2] = (bf16)v.z; p.b[3] = (bf16)v.w;
    ((uint2*)dst)[i] = p.u;
}

// ---------------------------------------------------------------- logits GEMM (fp32)
// 16 tokens x 32 experts per block; padded LDS (stride 33) -> conflict-free.
#define LT 16
__global__ __launch_bounds__(256) void logits_kernel(
    const float* __restrict__ X, const float* __restrict__ gw,
    float* __restrict__ logits)
{
    const int t0 = blockIdx.x * LT;
    __shared__ float Xs[LT][33];
    __shared__ float Ws[NE][33];
    const int tid = threadIdx.x;
    const int e = tid & 31, tsub = tid >> 5;   // tsub 0..7
    float acc0 = 0.f, acc1 = 0.f;

    for (int kt = 0; kt < DD; kt += 32) {
        #pragma unroll
        for (int i = 0; i < 2; ++i) {          // 16*32 = 512 elems
            int lin = tid + i * 256, r = lin >> 5, c = lin & 31;
            Xs[r][c] = X[(size_t)(t0 + r) * DD + kt + c];
        }
        #pragma unroll
        for (int i = 0; i < 4; ++i) {          // 32*32 = 1024 elems
            int lin = tid + i * 256, r = lin >> 5, c = lin & 31;
            Ws[r][c] = gw[(size_t)r * DD + kt + c];
        }
        __syncthreads();
        #pragma unroll
        for (int k = 0; k < 32; ++k) {
            float w = Ws[e][k];
            acc0 += Xs[tsub][k] * w;
            acc1 += Xs[tsub + 8][k] * w;
        }
        __syncthreads();
    }
    logits[(size_t)(t0 + tsub) * NE + e] = acc0;
    logits[(size_t)(t0 + tsub + 8) * NE + e] = acc1;
}

// ---------------------------------------------------------------- top-k routing
// one thread per token, fully unrolled (arrays stay in VGPRs)
__global__ __launch_bounds__(256) void topk_kernel(
    const float* __restrict__ logits, int* __restrict__ counts,
    int* __restrict__ toks, float* __restrict__ wts)
{
    const int t = blockIdx.x * 256 + threadIdx.x;
    float sc[NE];
    #pragma unroll
    for (int i = 0; i < NE; i += 4) {
        float4 v = *(const float4*)(logits + (size_t)t * NE + i);
        sc[i] = v.x; sc[i + 1] = v.y; sc[i + 2] = v.z; sc[i + 3] = v.w;
    }
    #pragma unroll
    for (int i = 0; i < NE; ++i) sc[i] = 1.f / (1.f + expf(-sc[i]));

    float gs[NGROUP];
    #pragma unroll
    for (int g = 0; g < NGROUP; ++g)
        gs[g] = sc[g * 4] + sc[g * 4 + 1] + sc[g * 4 + 2] + sc[g * 4 + 3];

    unsigned gmask = 0;
    #pragma unroll
    for (int it = 0; it < TOPKG; ++it) {       // strict > == first-index ties
        float bv = -1e30f; int bi = 0;
        #pragma unroll
        for (int g = 0; g < NGROUP; ++g) {
            bool c = !((gmask >> g) & 1) && gs[g] > bv;
            bv = c ? gs[g] : bv; bi = c ? g : bi;
        }
        gmask |= 1u << bi;
    }
    float ms[NE];
    #pragma unroll
    for (int i = 0; i < NE; ++i)
        ms[i] = ((gmask >> (i >> 2)) & 1) ? sc[i] : 0.f;

    int idx[TOPK]; float wv[TOPK]; float sum = 0.f; unsigned used = 0;
    #pragma unroll
    for (int it = 0; it < TOPK; ++it) {
        float bv = -1e30f; int bi = 0;
        #pragma unroll
        for (int i = 0; i < NE; ++i) {
            bool c = !((used >> i) & 1) && ms[i] > bv;
            bv = c ? ms[i] : bv; bi = c ? i : bi;
        }
        used |= 1u << bi; idx[it] = bi; wv[it] = bv; sum += bv;
    }
    float inv = 1.f / fmaxf(sum, 1e-12f);
    #pragma unroll
    for (int it = 0; it < TOPK; ++it) {
        int e = idx[it];
        int slot = atomicAdd(&counts[e], 1);
        toks[e * CAP + slot] = t;
        wts[e * CAP + slot] = wv[it] * inv;
    }
}

// ---------------------------------------------------------------- prefix offsets
__global__ void offsets_kernel(const int* __restrict__ counts, int* __restrict__ offsets) {
    if (threadIdx.x == 0) {
        int a = 0;
        for (int i = 0; i < NE1; ++i) { offsets[i] = a; a += counts[i]; }
    }
}

// ================================================================ bf16-weight path
// gate+up GEMM: A gathered token rows (bf16), B bf16 weights, global_load_lds staging.
__global__ __launch_bounds__(256) void gateup_b16(
    const bf16* __restrict__ Xb,
    const bf16* __restrict__ egb, const bf16* __restrict__ eub,
    const bf16* __restrict__ sgb, const bf16* __restrict__ sub_,
    const int* __restrict__ counts, const int* __restrict__ offsets,
    const int* __restrict__ toks, const float* __restrict__ wts,
    bf16* __restrict__ H)
{
    const int e = blockIdx.z;
    const int n_e = counts[e];
    const int m0 = blockIdx.y * BM;
    if (m0 >= n_e) return;
    const int offs = offsets[e];
    const int n0 = blockIdx.x * BN;
    const bf16* wg = (e < NE) ? egb + (size_t)e * II * DD : sgb;
    const bf16* wu = (e < NE) ? eub + (size_t)e * II * DD : sub_;

    __shared__ __align__(16) bf16 As[BM * BK2];
    __shared__ __align__(16) bf16 Bg[BN * BK2];
    __shared__ __align__(16) bf16 Bu[BN * BK2];
    __shared__ int   tokS[BM];
    __shared__ float wtS[BM];

    const int tid = threadIdx.x;
    if (tid < BM) {
        int r = m0 + tid;
        int tk = 0; float w = 0.f;
        if (r < n_e) { tk = toks[e * CAP + r]; w = wts[e * CAP + r]; }
        tokS[tid] = tk; wtS[tid] = w;
    }
    __syncthreads();

    const int lane = tid & 63;
    const int wv = tid >> 6;
    const int wm = (wv & 1) * 64;
    const int wn = (wv >> 1) * 32;
    const int lr = lane & 15;
    const int lq = lane >> 4;
    const int lsub = lane >> 3;        // 0..7: row within 8-row staging slab
    const int lcol = (lane & 7) * 8;   // element offset (16B chunk)

    // per-lane gathered A base addresses (row fixed across K)
    const bf16* aG[4];
    #pragma unroll
    for (int j = 0; j < 4; ++j) {
        int tk = tokS[(wv << 5) + j * 8 + lsub];
        aG[j] = Xb + (size_t)tk * DD + lcol;
    }
    const bf16* bG0 = wg + (size_t)(n0 + (wv << 4) + lsub) * DD + lcol;
    const bf16* bG1 = wg + (size_t)(n0 + (wv << 4) + 8 + lsub) * DD + lcol;
    const bf16* bU0 = wu + (size_t)(n0 + (wv << 4) + lsub) * DD + lcol;
    const bf16* bU1 = wu + (size_t)(n0 + (wv << 4) + 8 + lsub) * DD + lcol;

    f32x4 accG[4][2], accU[4][2];
    #pragma unroll
    for (int i = 0; i < 4; ++i)
        #pragma unroll
        for (int j = 0; j < 2; ++j) {
            accG[i][j] = f32x4{0.f, 0.f, 0.f, 0.f};
            accU[i][j] = f32x4{0.f, 0.f, 0.f, 0.f};
        }

    for (int kt = 0; kt < DD; kt += BK2) {
        #pragma unroll
        for (int j = 0; j < 4; ++j)
            GLDS(aG[j] + kt, As + ((wv << 5) + j * 8) * BK2);
        GLDS(bG0 + kt, Bg + ((wv << 4)) * BK2);
        GLDS(bG1 + kt, Bg + ((wv << 4) + 8) * BK2);
        GLDS(bU0 + kt, Bu + ((wv << 4)) * BK2);
        GLDS(bU1 + kt, Bu + ((wv << 4) + 8) * BK2);
        __syncthreads();

        #pragma unroll
        for (int ks = 0; ks < 2; ++ks) {
            bf16x8 af[4];
            #pragma unroll
            for (int mt = 0; mt < 4; ++mt)
                af[mt] = *(const bf16x8*)(As + (wm + mt * 16 + lr) * BK2 + ks * 32 + lq * 8);
            #pragma unroll
            for (int nt = 0; nt < 2; ++nt) {
                bf16x8 bg = *(const bf16x8*)(Bg + (wn + nt * 16 + lr) * BK2 + ks * 32 + lq * 8);
                bf16x8 bu = *(const bf16x8*)(Bu + (wn + nt * 16 + lr) * BK2 + ks * 32 + lq * 8);
                #pragma unroll
                for (int mt = 0; mt < 4; ++mt) {
                    accG[mt][nt] = __builtin_amdgcn_mfma_f32_16x16x32_bf16(af[mt], bg, accG[mt][nt], 0, 0, 0);
                    accU[mt][nt] = __builtin_amdgcn_mfma_f32_16x16x32_bf16(af[mt], bu, accU[mt][nt], 0, 0, 0);
                }
            }
        }
        __syncthreads();
    }

    #pragma unroll
    for (int mt = 0; mt < 4; ++mt) {
        #pragma unroll
        for (int r = 0; r < 4; ++r) {
            int mrow = wm + mt * 16 + lq * 4 + r;
            if (m0 + mrow < n_e) {
                float w = wtS[mrow];
                #pragma unroll
                for (int nt = 0; nt < 2; ++nt) {
                    float g = accG[mt][nt][r];
                    float u = accU[mt][nt][r];
                    float hval = g / (1.f + __expf(-g)) * u * w;
                    H[(size_t)(offs + m0 + mrow) * II + (n0 + wn + nt * 16 + lr)] = (bf16)hval;
                }
            }
        }
    }
}

// down GEMM + combine, bf16 weights, global_load_lds staging
__global__ __launch_bounds__(256) void down_b16(
    const bf16* __restrict__ H,
    const bf16* __restrict__ edb, const bf16* __restrict__ sdb,
    const int* __restrict__ counts, const int* __restrict__ offsets,
    const int* __restrict__ toks, float* __restrict__ out)
{
    const int e = blockIdx.z;
    const int n_e = counts[e];
    const int m0 = blockIdx.y * BM;
    if (m0 >= n_e) return;
    const int offs = offsets[e];
    const int n0 = blockIdx.x * BN;
    const bf16* wd = (e < NE) ? edb + (size_t)e * DD * II : sdb;

    __shared__ __align__(16) bf16 As[BM * BK2];
    __shared__ __align__(16) bf16 Bs[BN * BK2];
    __shared__ int tokS[BM];

    const int tid = threadIdx.x;
    if (tid < BM) {
        int r = m0 + tid;
        tokS[tid] = (r < n_e) ? toks[e * CAP + r] : 0;
    }
    __syncthreads();

    const int lane = tid & 63;
    const int wv = tid >> 6;
    const int wm = (wv & 1) * 64;
    const int wn = (wv >> 1) * 32;
    const int lr = lane & 15;
    const int lq = lane >> 4;
    const int lsub = lane >> 3;
    const int lcol = (lane & 7) * 8;

    const bf16* aG[4];
    #pragma unroll
    for (int j = 0; j < 4; ++j) {
        int r = m0 + (wv << 5) + j * 8 + lsub;
        if (r >= n_e) r = n_e - 1;           // clamp: padded rows never stored
        aG[j] = H + (size_t)(offs + r) * II + lcol;
    }
    const bf16* bD0 = wd + (size_t)(n0 + (wv << 4) + lsub) * II + lcol;
    const bf16* bD1 = wd + (size_t)(n0 + (wv << 4) + 8 + lsub) * II + lcol;

    f32x4 acc[4][2];
    #pragma unroll
    for (int i = 0; i < 4; ++i)
        #pragma unroll
        for (int j = 0; j < 2; ++j) acc[i][j] = f32x4{0.f, 0.f, 0.f, 0.f};

    for (int kt = 0; kt < II; kt += BK2) {
        #pragma unroll
        for (int j = 0; j < 4; ++j)
            GLDS(aG[j] + kt, As + ((wv << 5) + j * 8) * BK2);
        GLDS(bD0 + kt, Bs + ((wv << 4)) * BK2);
        GLDS(bD1 + kt, Bs + ((wv << 4) + 8) * BK2);
        __syncthreads();

        #pragma unroll
        for (int ks = 0; ks < 2; ++ks) {
            bf16x8 af[4];
            #pragma unroll
            for (int mt = 0; mt < 4; ++mt)
                af[mt] = *(const bf16x8*)(As + (wm + mt * 16 + lr) * BK2 + ks * 32 + lq * 8);
            #pragma unroll
            for (int nt = 0; nt < 2; ++nt) {
                bf16x8 bd = *(const bf16x8*)(Bs + (wn + nt * 16 + lr) * BK2 + ks * 32 + lq * 8);
                #pragma unroll
                for (int mt = 0; mt < 4; ++mt)
                    acc[mt][nt] = __builtin_amdgcn_mfma_f32_16x16x32_bf16(af[mt], bd, acc[mt][nt], 0, 0, 0);
            }
        }
        __syncthreads();
    }

    #pragma unroll
    for (int mt = 0; mt < 4; ++mt) {
        #pragma unroll
        for (int r = 0; r < 4; ++r) {
            int mrow = wm + mt * 16 + lq * 4 + r;
            if (m0 + mrow < n_e) {
                int tok = tokS[mrow];
                #pragma unroll
                for (int nt = 0; nt < 2; ++nt)
                    atomicAdd(out + (size_t)tok * DD + (n0 + wn + nt * 16 + lr),
                              acc[mt][nt][r]);
            }
        }
    }
}

// ================================================================ fallback path
// (fp32 weights, on-the-fly cvt staging — R0 kernels, used if ws too small)
__global__ __launch_bounds__(256) void gateup_kernel(
    const bf16* __restrict__ Xb,
    const float* __restrict__ eg, const float* __restrict__ eu,
    const float* __restrict__ sg, const float* __restrict__ su,
    const int* __restrict__ counts, const int* __restrict__ offsets,
    const int* __restrict__ toks, const float* __restrict__ wts,
    bf16* __restrict__ H)
{
    const int e = blockIdx.z;
    const int n_e = counts[e];
    const int m0 = blockIdx.y * BM;
    if (m0 >= n_e) return;
    const int offs = offsets[e];
    const int n0 = blockIdx.x * BN;
    const float* wg = (e < NE) ? eg + (size_t)e * II * DD : sg;
    const float* wu = (e < NE) ? eu + (size_t)e * II * DD : su;

    __shared__ __align__(16) bf16 As[BM * BK];
    __shared__ __align__(16) bf16 Bg[BN * BK];
    __shared__ __align__(16) bf16 Bu[BN * BK];
    __shared__ int   tokS[BM];
    __shared__ float wtS[BM];

    const int tid = threadIdx.x;
    if (tid < BM) {
        int r = m0 + tid;
        int tk = 0; float w = 0.f;
        if (r < n_e) { tk = toks[e * CAP + r]; w = wts[e * CAP + r]; }
        tokS[tid] = tk; wtS[tid] = w;
    }
    __syncthreads();

    const int lane = tid & 63;
    const int wv = tid >> 6;
    const int wm = (wv & 1) * 64;
    const int wn = (wv >> 1) * 32;
    const int lr = lane & 15;
    const int lq = lane >> 4;

    f32x4 accG[4][2], accU[4][2];
    #pragma unroll
    for (int i = 0; i < 4; ++i)
        #pragma unroll
        for (int j = 0; j < 2; ++j) {
            accG[i][j] = f32x4{0.f, 0.f, 0.f, 0.f};
            accU[i][j] = f32x4{0.f, 0.f, 0.f, 0.f};
        }

    const int srow = tid >> 2;
    const int skq  = (tid & 3) * 8;

    for (int kt = 0; kt < DD; kt += BK) {
        #pragma unroll
        for (int h = 0; h < 2; ++h) {
            int r = srow + h * 64;
            int tk = tokS[r];
            uint4 v = *(const uint4*)(Xb + (size_t)tk * DD + kt + skq);
            *(uint4*)(As + r * BK + skq) = v;
        }
        {
            const float* pg = wg + (size_t)(n0 + srow) * DD + kt + skq;
            float4 g0 = ((const float4*)pg)[0];
            float4 g1 = ((const float4*)pg)[1];
            bf16x8 vg;
            vg[0] = (bf16)g0.x; vg[1] = (bf16)g0.y; vg[2] = (bf16)g0.z; vg[3] = (bf16)g0.w;
            vg[4] = (bf16)g1.x; vg[5] = (bf16)g1.y; vg[6] = (bf16)g1.z; vg[7] = (bf16)g1.w;
            *(bf16x8*)(Bg + srow * BK + skq) = vg;
            const float* pu = wu + (size_t)(n0 + srow) * DD + kt + skq;
            float4 u0 = ((const float4*)pu)[0];
            float4 u1 = ((const float4*)pu)[1];
            bf16x8 vu;
            vu[0] = (bf16)u0.x; vu[1] = (bf16)u0.y; vu[2] = (bf16)u0.z; vu[3] = (bf16)u0.w;
            vu[4] = (bf16)u1.x; vu[5] = (bf16)u1.y; vu[6] = (bf16)u1.z; vu[7] = (bf16)u1.w;
            *(bf16x8*)(Bu + srow * BK + skq) = vu;
        }
        __syncthreads();

        bf16x8 af[4];
        #pragma unroll
        for (int mt = 0; mt < 4; ++mt)
            af[mt] = *(const bf16x8*)(As + (wm + mt * 16 + lr) * BK + lq * 8);
        #pragma unroll
        for (int nt = 0; nt < 2; ++nt) {
            bf16x8 bg = *(const bf16x8*)(Bg + (wn + nt * 16 + lr) * BK + lq * 8);
            bf16x8 bu = *(const bf16x8*)(Bu + (wn + nt * 16 + lr) * BK + lq * 8);
            #pragma unroll
            for (int mt = 0; mt < 4; ++mt) {
                accG[mt][nt] = __builtin_amdgcn_mfma_f32_16x16x32_bf16(af[mt], bg, accG[mt][nt], 0, 0, 0);
                accU[mt][nt] = __builtin_amdgcn_mfma_f32_16x16x32_bf16(af[mt], bu, accU[mt][nt], 0, 0, 0);
            }
        }
        __syncthreads();
    }

    #pragma unroll
    for (int mt = 0; mt < 4; ++mt) {
        #pragma unroll
        for (int r = 0; r < 4; ++r) {
            int mrow = wm + mt * 16 + lq * 4 + r;
            if (m0 + mrow < n_e) {
                float w = wtS[mrow];
                #pragma unroll
                for (int nt = 0; nt < 2; ++nt) {
                    float g = accG[mt][nt][r];
                    float u = accU[mt][nt][r];
                    float hval = g / (1.f + __expf(-g)) * u * w;
                    H[(size_t)(offs + m0 + mrow) * II + (n0 + wn + nt * 16 + lr)] = (bf16)hval;
                }
            }
        }
    }
}

__global__ __launch_bounds__(256) void down_kernel(
    const bf16* __restrict__ H,
    const float* __restrict__ ed, const float* __restrict__ sd,
    const int* __restrict__ counts, const int* __restrict__ offsets,
    const int* __restrict__ toks, float* __restrict__ out)
{
    const int e = blockIdx.z;
    const int n_e = counts[e];
    const int m0 = blockIdx.y * BM;
    if (m0 >= n_e) return;
    const int offs = offsets[e];
    const int n0 = blockIdx.x * BN;
    const float* wd = (e < NE) ? ed + (size_t)e * DD * II : sd;

    __shared__ __align__(16) bf16 As[BM * BK];
    __shared__ __align__(16) bf16 Bs[BN * BK];
    __shared__ int tokS[BM];

    const int tid = threadIdx.x;
    if (tid < BM) {
        int r = m0 + tid;
        tokS[tid] = (r < n_e) ? toks[e * CAP + r] : 0;
    }
    __syncthreads();

    const int lane = tid & 63;
    const int wv = tid >> 6;
    const int wm = (wv & 1) * 64;
    const int wn = (wv >> 1) * 32;
    const int lr = lane & 15;
    const int lq = lane >> 4;

    f32x4 acc[4][2];
    #pragma unroll
    for (int i = 0; i < 4; ++i)
        #pragma unroll
        for (int j = 0; j < 2; ++j) acc[i][j] = f32x4{0.f, 0.f, 0.f, 0.f};

    const int srow = tid >> 2;
    const int skq  = (tid & 3) * 8;

    for (int kt = 0; kt < II; kt += BK) {
        #pragma unroll
        for (int h = 0; h < 2; ++h) {
            int r = srow + h * 64;
            int hr = m0 + r; if (hr >= n_e) hr = n_e - 1;
            uint4 v = *(const uint4*)(H + (size_t)(offs + hr) * II + kt + skq);
            *(uint4*)(As + r * BK + skq) = v;
        }
        {
            const float* pd = wd + (size_t)(n0 + srow) * II + kt + skq;
            float4 d0 = ((const float4*)pd)[0];
            float4 d1 = ((const float4*)pd)[1];
            bf16x8 vd;
            vd[0] = (bf16)d0.x; vd[1] = (bf16)d0.y; vd[2] = (bf16)d0.z; vd[3] = (bf16)d0.w;
            vd[4] = (bf16)d1.x; vd[5] = (bf16)d1.y; vd[6] = (bf16)d1.z; vd[7] = (bf16)d1.w;
            *(bf16x8*)(Bs + srow * BK + skq) = vd;
        }
        __syncthreads();

        bf16x8 af[4];
        #pragma unroll
        for (int mt = 0; mt < 4; ++mt)
            af[mt] = *(const bf16x8*)(As + (wm + mt * 16 + lr) * BK + lq * 8);
        #pragma unroll
        for (int nt = 0; nt < 2; ++nt) {
            bf16x8 bd = *(const bf16x8*)(Bs + (wn + nt * 16 + lr) * BK + lq * 8);
            #pragma unroll
            for (int mt = 0; mt < 4; ++mt)
                acc[mt][nt] = __builtin_amdgcn_mfma_f32_16x16x32_bf16(af[mt], bd, acc[mt][nt], 0, 0, 0);
        }
        __syncthreads();
    }

    #pragma unroll
    for (int mt = 0; mt < 4; ++mt) {
        #pragma unroll
        for (int r = 0; r < 4; ++r) {
            int mrow = wm + mt * 16 + lq * 4 + r;
            if (m0 + mrow < n_e) {
                int tok = tokS[mrow];
                #pragma unroll
                for (int nt = 0; nt < 2; ++nt)
                    atomicAdd(out + (size_t)tok * DD + (n0 + wn + nt * 16 + lr),
                              acc[mt][nt][r]);
            }
        }
    }
}

// ---------------------------------------------------------------- launch
extern "C" void kernel_launch(void* const* d_in, const int* in_sizes, int n_in,
                              void* d_out, int out_size, void* d_ws, size_t ws_size,
                              hipStream_t stream) {
    if (ws_size < WS_MIN) return;

    const float* X  = (const float*)d_in[0];
    const float* gw = (const float*)d_in[1];
    const float* eg = (const float*)d_in[2];
    const float* eu = (const float*)d_in[3];
    const float* ed = (const float*)d_in[4];
    const float* sg = (const float*)d_in[5];
    const float* su = (const float*)d_in[6];
    const float* sd = (const float*)d_in[7];
    float* out = (float*)d_out;
    char* ws = (char*)d_ws;

    bf16*  Xb      = (bf16*)(ws + OFF_X);
    int*   counts  = (int*)(ws + OFF_COUNTS);
    int*   offsets = (int*)(ws + OFF_COUNTS + 256);
    int*   toks    = (int*)(ws + OFF_TOKS);
    float* wts     = (float*)(ws + OFF_WTS);
    bf16*  H       = (bf16*)(ws + OFF_H);
    float* logits  = out + (size_t)T_TOK * DD;

    const bool full = (ws_size >= WS_FULL);

    hipMemsetAsync(out, 0, (size_t)T_TOK * DD * sizeof(float), stream);
    init_kernel<<<16, 256, 0, stream>>>(counts, toks, wts);
    convert_kernel<<<(T_TOK * DD / 4) / 256, 256, 0, stream>>>(X, Xb);

    logits_kernel<<<T_TOK / LT, 256, 0, stream>>>(X, gw, logits);
    topk_kernel<<<T_TOK / 256, 256, 0, stream>>>(logits, counts, toks, wts);
    offsets_kernel<<<1, 64, 0, stream>>>(counts, offsets);

    if (full) {
        bf16* egb = (bf16*)(ws + OFF_EGB);
        bf16* eub = (bf16*)(ws + OFF_EUB);
        bf16* edb = (bf16*)(ws + OFF_EDB);
        bf16* sgb = (bf16*)(ws + OFF_SGB);
        bf16* sub_ = (bf16*)(ws + OFF_SUB);
        bf16* sdb = (bf16*)(ws + OFF_SDB);
        const int nw = NE * II * DD / 4 / 256;   // 16384 blocks
        const int ns = II * DD / 4 / 256;        // 512 blocks
        convert_kernel<<<nw, 256, 0, stream>>>(eg, egb);
        convert_kernel<<<nw, 256, 0, stream>>>(eu, eub);
        convert_kernel<<<nw, 256, 0, stream>>>(ed, edb);
        convert_kernel<<<ns, 256, 0, stream>>>(sg, sgb);
        convert_kernel<<<ns, 256, 0, stream>>>(su, sub_);
        convert_kernel<<<ns, 256, 0, stream>>>(sd, sdb);

        gateup_b16<<<dim3(II / BN, T_TOK / BM, NE1), 256, 0, stream>>>(
            Xb, egb, eub, sgb, sub_, counts, offsets, toks, wts, H);
        down_b16<<<dim3(DD / BN, T_TOK / BM, NE1), 256, 0, stream>>>(
            H, edb, sdb, counts, offsets, toks, out);
    } else {
        gateup_kernel<<<dim3(II / BN, T_TOK / BM, NE1), 256, 0, stream>>>(
            Xb, eg, eu, sg, su, counts, offsets, toks, wts, H);
        down_kernel<<<dim3(DD / BN, T_TOK / BM, NE1), 256, 0, stream>>>(
            H, ed, sd, counts, offsets, toks, out);
    }
}

// Round 3
// 599.049 us; speedup vs baseline: 1.2382x; 1.1506x over previous
//
#include <hip/hip_runtime.h>
#include <hip/hip_bf16.h>
#include <cstdint>
#include <cstddef>

// Problem constants
#define T_TOK 4096
#define DD    1024
#define II    512
#define NE    32     // routed experts
#define NE1   33     // + shared expert as expert 32
#define CAP   4096   // per-expert token-list capacity
#define NGROUP 8
#define TOPKG  4
#define TOPK   8

typedef __bf16 bf16;
typedef __bf16 bf16x4 __attribute__((ext_vector_type(4)));
typedef __bf16 bf16x8 __attribute__((ext_vector_type(8)));
typedef float  f32x4  __attribute__((ext_vector_type(4)));

// GEMM tile (fallback fp32-staging path)
#define BM 128
#define BN 64
#define BK 32
// bf16-weight path K tile
#define BK2 64

// Workspace layout (bytes)
#define OFF_X      0u               // T*D bf16 = 8,388,608
#define OFF_COUNTS 8388608u         // counts 33 ints @+0, offsets 34 ints @+256
#define OFF_TOKS   8389120u         // 33*4096 ints = 540,672
#define OFF_WTS    8929792u         // 33*4096 floats = 540,672
#define OFF_SRC    9470464u         // 4096*8 ints = 131,072 (packed e<<13|slot)
#define OFF_H      9601536u         // 36864*512 bf16 = 37,748,736
#define WS_MIN     47350272u
// bf16 weights (full path)
#define OFF_EGB    47350272u        // 32*512*1024*2 = 33,554,432
#define OFF_EUB    80904704u
#define OFF_EDB    114459136u
#define OFF_SGB    148013568u       // 512*1024*2 = 1,048,576
#define OFF_SUB    149062144u
#define OFF_SDB    150110720u
#define WS_FULL    151159296u
// per-(expert,slot) down partials (combine path)
#define OFF_HOUT   151159296u       // 36864*1024 bf16 = 75,497,472
#define WS_COMB    226656768u

// async global->LDS, 16B per lane; LDS dest must be wave-uniform base
#define GLDS(g, l) __builtin_amdgcn_global_load_lds( \
    (const __attribute__((address_space(1))) void*)(g), \
    (__attribute__((address_space(3))) void*)(l), 16, 0, 0)

// ---------------------------------------------------------------- init
__global__ void init_kernel(int* __restrict__ counts, int* __restrict__ toks,
                            float* __restrict__ wts) {
    int i = blockIdx.x * 256 + threadIdx.x;
    if (i < NE1) counts[i] = (i == NE) ? T_TOK : 0;
    if (i < T_TOK) {                       // shared expert token list
        toks[NE * CAP + i] = i;
        wts[NE * CAP + i] = 1.0f;
    }
}

// ---------------------------------------------------------------- fp32 -> bf16
__global__ void convert_kernel(const float* __restrict__ src, bf16* __restrict__ dst) {
    int i = blockIdx.x * 256 + threadIdx.x;   // i < n/4
    float4 v = ((const float4*)src)[i];
    union { bf16 b[4]; uint2 u; } p;
    p.b[0] = (bf16)v.x; p.b[1] = (bf16)v.y; p.b[2] = (bf16)v.z; p.b[3] = (bf16)v.w;
    ((uint2*)dst)[i] = p.u;
}

// ---------------------------------------------------------------- logits GEMM (fp32)
#define LT 16
__global__ __launch_bounds__(256) void logits_kernel(
    const float* __restrict__ X, const float* __restrict__ gw,
    float* __restrict__ logits)
{
    const int t0 = blockIdx.x * LT;
    __shared__ float Xs[LT][33];
    __shared__ float Ws[NE][33];
    const int tid = threadIdx.x;
    const int e = tid & 31, tsub = tid >> 5;   // tsub 0..7
    float acc0 = 0.f, acc1 = 0.f;

    for (int kt = 0; kt < DD; kt += 32) {
        #pragma unroll
        for (int i = 0; i < 2; ++i) {
            int lin = tid + i * 256, r = lin >> 5, c = lin & 31;
            Xs[r][c] = X[(size_t)(t0 + r) * DD + kt + c];
        }
        #pragma unroll
        for (int i = 0; i < 4; ++i) {
            int lin = tid + i * 256, r = lin >> 5, c = lin & 31;
            Ws[r][c] = gw[(size_t)r * DD + kt + c];
        }
        __syncthreads();
        #pragma unroll
        for (int k = 0; k < 32; ++k) {
            float w = Ws[e][k];
            acc0 += Xs[tsub][k] * w;
            acc1 += Xs[tsub + 8][k] * w;
        }
        __syncthreads();
    }
    logits[(size_t)(t0 + tsub) * NE + e] = acc0;
    logits[(size_t)(t0 + tsub + 8) * NE + e] = acc1;
}

// ---------------------------------------------------------------- top-k routing
__global__ __launch_bounds__(256) void topk_kernel(
    const float* __restrict__ logits, int* __restrict__ counts,
    int* __restrict__ toks, float* __restrict__ wts, int* __restrict__ srcs)
{
    const int t = blockIdx.x * 256 + threadIdx.x;
    float sc[NE];
    #pragma unroll
    for (int i = 0; i < NE; i += 4) {
        float4 v = *(const float4*)(logits + (size_t)t * NE + i);
        sc[i] = v.x; sc[i + 1] = v.y; sc[i + 2] = v.z; sc[i + 3] = v.w;
    }
    #pragma unroll
    for (int i = 0; i < NE; ++i) sc[i] = 1.f / (1.f + expf(-sc[i]));

    float gs[NGROUP];
    #pragma unroll
    for (int g = 0; g < NGROUP; ++g)
        gs[g] = sc[g * 4] + sc[g * 4 + 1] + sc[g * 4 + 2] + sc[g * 4 + 3];

    unsigned gmask = 0;
    #pragma unroll
    for (int it = 0; it < TOPKG; ++it) {       // strict > == first-index ties
        float bv = -1e30f; int bi = 0;
        #pragma unroll
        for (int g = 0; g < NGROUP; ++g) {
            bool c = !((gmask >> g) & 1) && gs[g] > bv;
            bv = c ? gs[g] : bv; bi = c ? g : bi;
        }
        gmask |= 1u << bi;
    }
    float ms[NE];
    #pragma unroll
    for (int i = 0; i < NE; ++i)
        ms[i] = ((gmask >> (i >> 2)) & 1) ? sc[i] : 0.f;

    int idx[TOPK]; float wv[TOPK]; float sum = 0.f; unsigned used = 0;
    #pragma unroll
    for (int it = 0; it < TOPK; ++it) {
        float bv = -1e30f; int bi = 0;
        #pragma unroll
        for (int i = 0; i < NE; ++i) {
            bool c = !((used >> i) & 1) && ms[i] > bv;
            bv = c ? ms[i] : bv; bi = c ? i : bi;
        }
        used |= 1u << bi; idx[it] = bi; wv[it] = bv; sum += bv;
    }
    float inv = 1.f / fmaxf(sum, 1e-12f);
    #pragma unroll
    for (int it = 0; it < TOPK; ++it) {
        int e = idx[it];
        int slot = atomicAdd(&counts[e], 1);
        toks[e * CAP + slot] = t;
        wts[e * CAP + slot] = wv[it] * inv;
        srcs[t * TOPK + it] = (e << 13) | slot;   // for combine gather
    }
}

// ---------------------------------------------------------------- prefix offsets
__global__ void offsets_kernel(const int* __restrict__ counts, int* __restrict__ offsets) {
    if (threadIdx.x == 0) {
        int a = 0;
        for (int i = 0; i < NE1; ++i) { offsets[i] = a; a += counts[i]; }
    }
}

// ================================================================ bf16-weight path
// LDS layout XOR-swizzle: 16B chunk c of row r lives at chunk c^(r&7).
// Staging: lane l (chunk l&7, row-in-slab l>>3) reads global chunk (l&7)^(l>>3).
// Fragment reads: chunk (ks*4+lq)^(lr&7) -> 2 lanes/bank-group (free).
__global__ __launch_bounds__(256) void gateup_b16(
    const bf16* __restrict__ Xb,
    const bf16* __restrict__ egb, const bf16* __restrict__ eub,
    const bf16* __restrict__ sgb, const bf16* __restrict__ sub_,
    const int* __restrict__ counts, const int* __restrict__ offsets,
    const int* __restrict__ toks, const float* __restrict__ wts,
    bf16* __restrict__ H)
{
    const int e = blockIdx.z;
    const int n_e = counts[e];
    const int m0 = blockIdx.y * BM;
    if (m0 >= n_e) return;
    const int offs = offsets[e];
    const int n0 = blockIdx.x * BN;
    const bf16* wg = (e < NE) ? egb + (size_t)e * II * DD : sgb;
    const bf16* wu = (e < NE) ? eub + (size_t)e * II * DD : sub_;

    __shared__ __align__(16) bf16 As[BM * BK2];
    __shared__ __align__(16) bf16 Bg[BN * BK2];
    __shared__ __align__(16) bf16 Bu[BN * BK2];
    __shared__ int   tokS[BM];
    __shared__ float wtS[BM];

    const int tid = threadIdx.x;
    if (tid < BM) {
        int r = m0 + tid;
        int tk = 0; float w = 0.f;
        if (r < n_e) { tk = toks[e * CAP + r]; w = wts[e * CAP + r]; }
        tokS[tid] = tk; wtS[tid] = w;
    }
    __syncthreads();

    const int lane = tid & 63;
    const int wv = tid >> 6;
    const int wm = (wv & 1) * 64;
    const int wn = (wv >> 1) * 32;
    const int lr = lane & 15;
    const int lq = lane >> 4;
    const int lsub = lane >> 3;                    // 0..7: row within 8-row slab
    const int lcol = (((lane & 7) ^ lsub)) * 8;    // swizzled 16B chunk

    const bf16* aG[4];
    #pragma unroll
    for (int j = 0; j < 4; ++j) {
        int tk = tokS[(wv << 5) + j * 8 + lsub];
        aG[j] = Xb + (size_t)tk * DD + lcol;
    }
    const bf16* bG0 = wg + (size_t)(n0 + (wv << 4) + lsub) * DD + lcol;
    const bf16* bG1 = wg + (size_t)(n0 + (wv << 4) + 8 + lsub) * DD + lcol;
    const bf16* bU0 = wu + (size_t)(n0 + (wv << 4) + lsub) * DD + lcol;
    const bf16* bU1 = wu + (size_t)(n0 + (wv << 4) + 8 + lsub) * DD + lcol;

    // swizzled fragment-read chunk offsets (elements)
    const int cs0 = ((0 * 4 + lq) ^ (lr & 7)) * 8;
    const int cs1 = ((1 * 4 + lq) ^ (lr & 7)) * 8;

    f32x4 accG[4][2], accU[4][2];
    #pragma unroll
    for (int i = 0; i < 4; ++i)
        #pragma unroll
        for (int j = 0; j < 2; ++j) {
            accG[i][j] = f32x4{0.f, 0.f, 0.f, 0.f};
            accU[i][j] = f32x4{0.f, 0.f, 0.f, 0.f};
        }

    for (int kt = 0; kt < DD; kt += BK2) {
        #pragma unroll
        for (int j = 0; j < 4; ++j)
            GLDS(aG[j] + kt, As + ((wv << 5) + j * 8) * BK2);
        GLDS(bG0 + kt, Bg + ((wv << 4)) * BK2);
        GLDS(bG1 + kt, Bg + ((wv << 4) + 8) * BK2);
        GLDS(bU0 + kt, Bu + ((wv << 4)) * BK2);
        GLDS(bU1 + kt, Bu + ((wv << 4) + 8) * BK2);
        __syncthreads();

        #pragma unroll
        for (int ks = 0; ks < 2; ++ks) {
            const int cs = ks ? cs1 : cs0;
            bf16x8 af[4];
            #pragma unroll
            for (int mt = 0; mt < 4; ++mt)
                af[mt] = *(const bf16x8*)(As + (wm + mt * 16 + lr) * BK2 + cs);
            #pragma unroll
            for (int nt = 0; nt < 2; ++nt) {
                bf16x8 bg = *(const bf16x8*)(Bg + (wn + nt * 16 + lr) * BK2 + cs);
                bf16x8 bu = *(const bf16x8*)(Bu + (wn + nt * 16 + lr) * BK2 + cs);
                #pragma unroll
                for (int mt = 0; mt < 4; ++mt) {
                    accG[mt][nt] = __builtin_amdgcn_mfma_f32_16x16x32_bf16(af[mt], bg, accG[mt][nt], 0, 0, 0);
                    accU[mt][nt] = __builtin_amdgcn_mfma_f32_16x16x32_bf16(af[mt], bu, accU[mt][nt], 0, 0, 0);
                }
            }
        }
        __syncthreads();
    }

    #pragma unroll
    for (int mt = 0; mt < 4; ++mt) {
        #pragma unroll
        for (int r = 0; r < 4; ++r) {
            int mrow = wm + mt * 16 + lq * 4 + r;
            if (m0 + mrow < n_e) {
                float w = wtS[mrow];
                #pragma unroll
                for (int nt = 0; nt < 2; ++nt) {
                    float g = accG[mt][nt][r];
                    float u = accU[mt][nt][r];
                    float hval = g / (1.f + __expf(-g)) * u * w;
                    H[(size_t)(offs + m0 + mrow) * II + (n0 + wn + nt * 16 + lr)] = (bf16)hval;
                }
            }
        }
    }
}

// down GEMM: bf16 weights, swizzled LDS; epilogue either plain bf16 stores to
// Hout (combine path) or fp32 atomics to out (fallback).
__global__ __launch_bounds__(256) void down_b16(
    const bf16* __restrict__ H,
    const bf16* __restrict__ edb, const bf16* __restrict__ sdb,
    const int* __restrict__ counts, const int* __restrict__ offsets,
    const int* __restrict__ toks, float* __restrict__ out,
    bf16* __restrict__ Hout, int use_hout)
{
    const int e = blockIdx.z;
    const int n_e = counts[e];
    const int m0 = blockIdx.y * BM;
    if (m0 >= n_e) return;
    const int offs = offsets[e];
    const int n0 = blockIdx.x * BN;
    const bf16* wd = (e < NE) ? edb + (size_t)e * DD * II : sdb;

    __shared__ __align__(16) bf16 As[BM * BK2];
    __shared__ __align__(16) bf16 Bs[BN * BK2];
    __shared__ int tokS[BM];

    const int tid = threadIdx.x;
    if (tid < BM) {
        int r = m0 + tid;
        tokS[tid] = (r < n_e) ? toks[e * CAP + r] : 0;
    }
    __syncthreads();

    const int lane = tid & 63;
    const int wv = tid >> 6;
    const int wm = (wv & 1) * 64;
    const int wn = (wv >> 1) * 32;
    const int lr = lane & 15;
    const int lq = lane >> 4;
    const int lsub = lane >> 3;
    const int lcol = (((lane & 7) ^ lsub)) * 8;

    const bf16* aG[4];
    #pragma unroll
    for (int j = 0; j < 4; ++j) {
        int r = m0 + (wv << 5) + j * 8 + lsub;
        if (r >= n_e) r = n_e - 1;           // clamp: padded rows never stored
        aG[j] = H + (size_t)(offs + r) * II + lcol;
    }
    const bf16* bD0 = wd + (size_t)(n0 + (wv << 4) + lsub) * II + lcol;
    const bf16* bD1 = wd + (size_t)(n0 + (wv << 4) + 8 + lsub) * II + lcol;

    const int cs0 = ((0 * 4 + lq) ^ (lr & 7)) * 8;
    const int cs1 = ((1 * 4 + lq) ^ (lr & 7)) * 8;

    f32x4 acc[4][2];
    #pragma unroll
    for (int i = 0; i < 4; ++i)
        #pragma unroll
        for (int j = 0; j < 2; ++j) acc[i][j] = f32x4{0.f, 0.f, 0.f, 0.f};

    for (int kt = 0; kt < II; kt += BK2) {
        #pragma unroll
        for (int j = 0; j < 4; ++j)
            GLDS(aG[j] + kt, As + ((wv << 5) + j * 8) * BK2);
        GLDS(bD0 + kt, Bs + ((wv << 4)) * BK2);
        GLDS(bD1 + kt, Bs + ((wv << 4) + 8) * BK2);
        __syncthreads();

        #pragma unroll
        for (int ks = 0; ks < 2; ++ks) {
            const int cs = ks ? cs1 : cs0;
            bf16x8 af[4];
            #pragma unroll
            for (int mt = 0; mt < 4; ++mt)
                af[mt] = *(const bf16x8*)(As + (wm + mt * 16 + lr) * BK2 + cs);
            #pragma unroll
            for (int nt = 0; nt < 2; ++nt) {
                bf16x8 bd = *(const bf16x8*)(Bs + (wn + nt * 16 + lr) * BK2 + cs);
                #pragma unroll
                for (int mt = 0; mt < 4; ++mt)
                    acc[mt][nt] = __builtin_amdgcn_mfma_f32_16x16x32_bf16(af[mt], bd, acc[mt][nt], 0, 0, 0);
            }
        }
        __syncthreads();
    }

    #pragma unroll
    for (int mt = 0; mt < 4; ++mt) {
        #pragma unroll
        for (int r = 0; r < 4; ++r) {
            int mrow = wm + mt * 16 + lq * 4 + r;
            if (m0 + mrow < n_e) {
                if (use_hout) {
                    #pragma unroll
                    for (int nt = 0; nt < 2; ++nt)
                        Hout[(size_t)(offs + m0 + mrow) * DD + (n0 + wn + nt * 16 + lr)] =
                            (bf16)acc[mt][nt][r];
                } else {
                    int tok = tokS[mrow];
                    #pragma unroll
                    for (int nt = 0; nt < 2; ++nt)
                        atomicAdd(out + (size_t)tok * DD + (n0 + wn + nt * 16 + lr),
                                  acc[mt][nt][r]);
                }
            }
        }
    }
}

// ---------------------------------------------------------------- combine
// out[t] = sum of 9 Hout rows (8 routed via srcs, shared at offsets[NE]+t)
__global__ __launch_bounds__(256) void combine_kernel(
    const bf16* __restrict__ Hout, const int* __restrict__ srcs,
    const int* __restrict__ offsets, float* __restrict__ out)
{
    const int t = blockIdx.x;
    const int tid = threadIdx.x;
    __shared__ int rowS[9];
    if (tid < TOPK) {
        int p = srcs[t * TOPK + tid];
        rowS[tid] = offsets[p >> 13] + (p & 8191);
    } else if (tid == TOPK) {
        rowS[TOPK] = offsets[NE] + t;
    }
    __syncthreads();
    const int c0 = tid * 4;
    float4 acc = {0.f, 0.f, 0.f, 0.f};
    #pragma unroll
    for (int k = 0; k < 9; ++k) {
        bf16x4 v = *(const bf16x4*)(Hout + (size_t)rowS[k] * DD + c0);
        acc.x += (float)v[0]; acc.y += (float)v[1];
        acc.z += (float)v[2]; acc.w += (float)v[3];
    }
    *(float4*)(out + (size_t)t * DD + c0) = acc;
}

// ================================================================ fallback path
// (fp32 weights, on-the-fly cvt staging — used only if ws too small)
__global__ __launch_bounds__(256) void gateup_kernel(
    const bf16* __restrict__ Xb,
    const float* __restrict__ eg, const float* __restrict__ eu,
    const float* __restrict__ sg, const float* __restrict__ su,
    const int* __restrict__ counts, const int* __restrict__ offsets,
    const int* __restrict__ toks, const float* __restrict__ wts,
    bf16* __restrict__ H)
{
    const int e = blockIdx.z;
    const int n_e = counts[e];
    const int m0 = blockIdx.y * BM;
    if (m0 >= n_e) return;
    const int offs = offsets[e];
    const int n0 = blockIdx.x * BN;
    const float* wg = (e < NE) ? eg + (size_t)e * II * DD : sg;
    const float* wu = (e < NE) ? eu + (size_t)e * II * DD : su;

    __shared__ __align__(16) bf16 As[BM * BK];
    __shared__ __align__(16) bf16 Bg[BN * BK];
    __shared__ __align__(16) bf16 Bu[BN * BK];
    __shared__ int   tokS[BM];
    __shared__ float wtS[BM];

    const int tid = threadIdx.x;
    if (tid < BM) {
        int r = m0 + tid;
        int tk = 0; float w = 0.f;
        if (r < n_e) { tk = toks[e * CAP + r]; w = wts[e * CAP + r]; }
        tokS[tid] = tk; wtS[tid] = w;
    }
    __syncthreads();

    const int lane = tid & 63;
    const int wv = tid >> 6;
    const int wm = (wv & 1) * 64;
    const int wn = (wv >> 1) * 32;
    const int lr = lane & 15;
    const int lq = lane >> 4;

    f32x4 accG[4][2], accU[4][2];
    #pragma unroll
    for (int i = 0; i < 4; ++i)
        #pragma unroll
        for (int j = 0; j < 2; ++j) {
            accG[i][j] = f32x4{0.f, 0.f, 0.f, 0.f};
            accU[i][j] = f32x4{0.f, 0.f, 0.f, 0.f};
        }

    const int srow = tid >> 2;
    const int skq  = (tid & 3) * 8;

    for (int kt = 0; kt < DD; kt += BK) {
        #pragma unroll
        for (int h = 0; h < 2; ++h) {
            int r = srow + h * 64;
            int tk = tokS[r];
            uint4 v = *(const uint4*)(Xb + (size_t)tk * DD + kt + skq);
            *(uint4*)(As + r * BK + skq) = v;
        }
        {
            const float* pg = wg + (size_t)(n0 + srow) * DD + kt + skq;
            float4 g0 = ((const float4*)pg)[0];
            float4 g1 = ((const float4*)pg)[1];
            bf16x8 vg;
            vg[0] = (bf16)g0.x; vg[1] = (bf16)g0.y; vg[2] = (bf16)g0.z; vg[3] = (bf16)g0.w;
            vg[4] = (bf16)g1.x; vg[5] = (bf16)g1.y; vg[6] = (bf16)g1.z; vg[7] = (bf16)g1.w;
            *(bf16x8*)(Bg + srow * BK + skq) = vg;
            const float* pu = wu + (size_t)(n0 + srow) * DD + kt + skq;
            float4 u0 = ((const float4*)pu)[0];
            float4 u1 = ((const float4*)pu)[1];
            bf16x8 vu;
            vu[0] = (bf16)u0.x; vu[1] = (bf16)u0.y; vu[2] = (bf16)u0.z; vu[3] = (bf16)u0.w;
            vu[4] = (bf16)u1.x; vu[5] = (bf16)u1.y; vu[6] = (bf16)u1.z; vu[7] = (bf16)u1.w;
            *(bf16x8*)(Bu + srow * BK + skq) = vu;
        }
        __syncthreads();

        bf16x8 af[4];
        #pragma unroll
        for (int mt = 0; mt < 4; ++mt)
            af[mt] = *(const bf16x8*)(As + (wm + mt * 16 + lr) * BK + lq * 8);
        #pragma unroll
        for (int nt = 0; nt < 2; ++nt) {
            bf16x8 bg = *(const bf16x8*)(Bg + (wn + nt * 16 + lr) * BK + lq * 8);
            bf16x8 bu = *(const bf16x8*)(Bu + (wn + nt * 16 + lr) * BK + lq * 8);
            #pragma unroll
            for (int mt = 0; mt < 4; ++mt) {
                accG[mt][nt] = __builtin_amdgcn_mfma_f32_16x16x32_bf16(af[mt], bg, accG[mt][nt], 0, 0, 0);
                accU[mt][nt] = __builtin_amdgcn_mfma_f32_16x16x32_bf16(af[mt], bu, accU[mt][nt], 0, 0, 0);
            }
        }
        __syncthreads();
    }

    #pragma unroll
    for (int mt = 0; mt < 4; ++mt) {
        #pragma unroll
        for (int r = 0; r < 4; ++r) {
            int mrow = wm + mt * 16 + lq * 4 + r;
            if (m0 + mrow < n_e) {
                float w = wtS[mrow];
                #pragma unroll
                for (int nt = 0; nt < 2; ++nt) {
                    float g = accG[mt][nt][r];
                    float u = accU[mt][nt][r];
                    float hval = g / (1.f + __expf(-g)) * u * w;
                    H[(size_t)(offs + m0 + mrow) * II + (n0 + wn + nt * 16 + lr)] = (bf16)hval;
                }
            }
        }
    }
}

__global__ __launch_bounds__(256) void down_kernel(
    const bf16* __restrict__ H,
    const float* __restrict__ ed, const float* __restrict__ sd,
    const int* __restrict__ counts, const int* __restrict__ offsets,
    const int* __restrict__ toks, float* __restrict__ out)
{
    const int e = blockIdx.z;
    const int n_e = counts[e];
    const int m0 = blockIdx.y * BM;
    if (m0 >= n_e) return;
    const int offs = offsets[e];
    const int n0 = blockIdx.x * BN;
    const float* wd = (e < NE) ? ed + (size_t)e * DD * II : sd;

    __shared__ __align__(16) bf16 As[BM * BK];
    __shared__ __align__(16) bf16 Bs[BN * BK];
    __shared__ int tokS[BM];

    const int tid = threadIdx.x;
    if (tid < BM) {
        int r = m0 + tid;
        tokS[tid] = (r < n_e) ? toks[e * CAP + r] : 0;
    }
    __syncthreads();

    const int lane = tid & 63;
    const int wv = tid >> 6;
    const int wm = (wv & 1) * 64;
    const int wn = (wv >> 1) * 32;
    const int lr = lane & 15;
    const int lq = lane >> 4;

    f32x4 acc[4][2];
    #pragma unroll
    for (int i = 0; i < 4; ++i)
        #pragma unroll
        for (int j = 0; j < 2; ++j) acc[i][j] = f32x4{0.f, 0.f, 0.f, 0.f};

    const int srow = tid >> 2;
    const int skq  = (tid & 3) * 8;

    for (int kt = 0; kt < II; kt += BK) {
        #pragma unroll
        for (int h = 0; h < 2; ++h) {
            int r = srow + h * 64;
            int hr = m0 + r; if (hr >= n_e) hr = n_e - 1;
            uint4 v = *(const uint4*)(H + (size_t)(offs + hr) * II + kt + skq);
            *(uint4*)(As + r * BK + skq) = v;
        }
        {
            const float* pd = wd + (size_t)(n0 + srow) * II + kt + skq;
            float4 d0 = ((const float4*)pd)[0];
            float4 d1 = ((const float4*)pd)[1];
            bf16x8 vd;
            vd[0] = (bf16)d0.x; vd[1] = (bf16)d0.y; vd[2] = (bf16)d0.z; vd[3] = (bf16)d0.w;
            vd[4] = (bf16)d1.x; vd[5] = (bf16)d1.y; vd[6] = (bf16)d1.z; vd[7] = (bf16)d1.w;
            *(bf16x8*)(Bs + srow * BK + skq) = vd;
        }
        __syncthreads();

        bf16x8 af[4];
        #pragma unroll
        for (int mt = 0; mt < 4; ++mt)
            af[mt] = *(const bf16x8*)(As + (wm + mt * 16 + lr) * BK + lq * 8);
        #pragma unroll
        for (int nt = 0; nt < 2; ++nt) {
            bf16x8 bd = *(const bf16x8*)(Bs + (wn + nt * 16 + lr) * BK + lq * 8);
            #pragma unroll
            for (int mt = 0; mt < 4; ++mt)
                acc[mt][nt] = __builtin_amdgcn_mfma_f32_16x16x32_bf16(af[mt], bd, acc[mt][nt], 0, 0, 0);
        }
        __syncthreads();
    }

    #pragma unroll
    for (int mt = 0; mt < 4; ++mt) {
        #pragma unroll
        for (int r = 0; r < 4; ++r) {
            int mrow = wm + mt * 16 + lq * 4 + r;
            if (m0 + mrow < n_e) {
                int tok = tokS[mrow];
                #pragma unroll
                for (int nt = 0; nt < 2; ++nt)
                    atomicAdd(out + (size_t)tok * DD + (n0 + wn + nt * 16 + lr),
                              acc[mt][nt][r]);
            }
        }
    }
}

// ---------------------------------------------------------------- launch
extern "C" void kernel_launch(void* const* d_in, const int* in_sizes, int n_in,
                              void* d_out, int out_size, void* d_ws, size_t ws_size,
                              hipStream_t stream) {
    if (ws_size < WS_MIN) return;

    const float* X  = (const float*)d_in[0];
    const float* gw = (const float*)d_in[1];
    const float* eg = (const float*)d_in[2];
    const float* eu = (const float*)d_in[3];
    const float* ed = (const float*)d_in[4];
    const float* sg = (const float*)d_in[5];
    const float* su = (const float*)d_in[6];
    const float* sd = (const float*)d_in[7];
    float* out = (float*)d_out;
    char* ws = (char*)d_ws;

    bf16*  Xb      = (bf16*)(ws + OFF_X);
    int*   counts  = (int*)(ws + OFF_COUNTS);
    int*   offsets = (int*)(ws + OFF_COUNTS + 256);
    int*   toks    = (int*)(ws + OFF_TOKS);
    float* wts     = (float*)(ws + OFF_WTS);
    int*   srcs    = (int*)(ws + OFF_SRC);
    bf16*  H       = (bf16*)(ws + OFF_H);
    float* logits  = out + (size_t)T_TOK * DD;

    const bool full = (ws_size >= WS_FULL);
    const bool comb = (ws_size >= WS_COMB);

    if (!comb)   // combine path overwrites out fully; others accumulate
        hipMemsetAsync(out, 0, (size_t)T_TOK * DD * sizeof(float), stream);
    init_kernel<<<16, 256, 0, stream>>>(counts, toks, wts);
    convert_kernel<<<(T_TOK * DD / 4) / 256, 256, 0, stream>>>(X, Xb);

    logits_kernel<<<T_TOK / LT, 256, 0, stream>>>(X, gw, logits);
    topk_kernel<<<T_TOK / 256, 256, 0, stream>>>(logits, counts, toks, wts, srcs);
    offsets_kernel<<<1, 64, 0, stream>>>(counts, offsets);

    if (full) {
        bf16* egb = (bf16*)(ws + OFF_EGB);
        bf16* eub = (bf16*)(ws + OFF_EUB);
        bf16* edb = (bf16*)(ws + OFF_EDB);
        bf16* sgb = (bf16*)(ws + OFF_SGB);
        bf16* sub_ = (bf16*)(ws + OFF_SUB);
        bf16* sdb = (bf16*)(ws + OFF_SDB);
        bf16* Hout = (bf16*)(ws + OFF_HOUT);
        const int nw = NE * II * DD / 4 / 256;
        const int ns = II * DD / 4 / 256;
        convert_kernel<<<nw, 256, 0, stream>>>(eg, egb);
        convert_kernel<<<nw, 256, 0, stream>>>(eu, eub);
        convert_kernel<<<nw, 256, 0, stream>>>(ed, edb);
        convert_kernel<<<ns, 256, 0, stream>>>(sg, sgb);
        convert_kernel<<<ns, 256, 0, stream>>>(su, sub_);
        convert_kernel<<<ns, 256, 0, stream>>>(sd, sdb);

        gateup_b16<<<dim3(II / BN, T_TOK / BM, NE1), 256, 0, stream>>>(
            Xb, egb, eub, sgb, sub_, counts, offsets, toks, wts, H);
        down_b16<<<dim3(DD / BN, T_TOK / BM, NE1), 256, 0, stream>>>(
            H, edb, sdb, counts, offsets, toks, out, Hout, comb ? 1 : 0);
        if (comb)
            combine_kernel<<<T_TOK, 256, 0, stream>>>(Hout, srcs, offsets, out);
    } else {
        gateup_kernel<<<dim3(II / BN, T_TOK / BM, NE1), 256, 0, stream>>>(
            Xb, eg, eu, sg, su, counts, offsets, toks, wts, H);
        down_kernel<<<dim3(DD / BN, T_TOK / BM, NE1), 256, 0, stream>>>(
            H, ed, sd, counts, offsets, toks, out);
    }
}